// Round 3
// baseline (1942.656 us; speedup 1.0000x reference)
//
#include <hip/hip_runtime.h>
#include <hip/hip_bf16.h>

#define NN 100000
#define NE 1600000

using bf16 = __hip_bfloat16;
static __device__ __forceinline__ float b2f(bf16 v){ return __bfloat162float(v); }
static __device__ __forceinline__ bf16 f2b(float v){ return __float2bfloat16(v); }

// canonical f32 weight-pool offsets (floats)
#define W1F   0
#define B1F   128
#define W2F   192
#define B2F   4288
#define W3F   4352
#define B3F   8448
#define FW1F  8512
#define FB1F  16704
#define FW2F  16832
#define FB2F  20928
#define WTOT  20960

// ---- dtype sniff: even ushort slots of f32 storage are low-mantissa bits ->
// exponent-field 0xFF/0x00 appears ~0.8% of the time; true bf16 N(0,1) never.
__global__ void k_sniff(const unsigned short* __restrict__ xr, int* flag){
  __shared__ int found;
  if(threadIdx.x==0) found = 0;
  __syncthreads();
  int loc = 0;
  for(int i=threadIdx.x*2; i<200000; i+=2048){
    unsigned e = (xr[i]>>7)&0xFF;
    if(e==0xFFu || e==0u) loc = 1;
  }
  if(loc) found = 1;            // benign same-value race
  __syncthreads();
  if(threadIdx.x==0) *flag = found;   // 1 = f32 storage, 0 = bf16 storage
}

// convert all weights/biases into canonical f32 pool
__global__ void k_convert_w(const void* p0,const void* p1,const void* p2,const void* p3,
                            const void* p4,const void* p5,const void* p6,const void* p7,
                            const void* p8,const void* p9,
                            const int* __restrict__ flag, float* __restrict__ Wc){
  const void* ps[10] = {p0,p1,p2,p3,p4,p5,p6,p7,p8,p9};
  const int off[11] = {W1F,B1F,W2F,B2F,W3F,B3F,FW1F,FB1F,FW2F,FB2F,WTOT};
  int f = *flag;
  for(int t=threadIdx.x; t<WTOT; t+=256){
    int seg = 0;
    while(off[seg+1] <= t) seg++;
    int j = t - off[seg];
    Wc[t] = f ? ((const float*)ps[seg])[j] : b2f(((const bf16*)ps[seg])[j]);
  }
}

__global__ void k_deg_init(float* deg){
  int i = blockIdx.x*256 + threadIdx.x;
  if(i < NN) deg[i] = 1.0f;           // self-loop
}
__global__ void k_deg_acc(const int* __restrict__ dst, float* __restrict__ deg){
  int e = blockIdx.x*256 + threadIdx.x;
  if(e < NE) atomicAdd(&deg[dst[e]], 1.0f);
}
__global__ void k_dinv(float* deg){
  int i = blockIdx.x*256 + threadIdx.x;
  if(i < NN) deg[i] = 1.0f / sqrtf(deg[i]);   // deg >= 1 always
}

// layer 1: s = dinv * (x @ W1)  (x is N x 2), agg = 0
__global__ void k_transform1(const void* __restrict__ xv, const float* __restrict__ W1c,
                             const int* __restrict__ flag, const float* __restrict__ dinv,
                             bf16* __restrict__ s, float* __restrict__ agg){
  int t = blockIdx.x*256 + threadIdx.x;   // grid exactly NN*64 threads
  int i = t>>6, c = t&63;
  float x0, x1;
  if(*flag){ const float* xp=(const float*)xv; x0=xp[2*i]; x1=xp[2*i+1]; }
  else     { const bf16*  xp=(const bf16*)xv;  x0=b2f(xp[2*i]); x1=b2f(xp[2*i+1]); }
  float v = x0*W1c[c] + x1*W1c[64+c];
  s[t] = f2b(v * dinv[i]);
  agg[t] = 0.0f;
}

// 64->64 transform: s = dinv * (h @ W), agg = 0
__global__ void k_transform64(const bf16* __restrict__ h, const float* __restrict__ W,
                              const float* __restrict__ dinv,
                              bf16* __restrict__ s, float* __restrict__ agg){
  __shared__ float Ws[64*64];
  for(int j=threadIdx.x; j<64*64; j+=256) Ws[j] = W[j];
  __syncthreads();
  int t = blockIdx.x*256 + threadIdx.x;   // grid exactly NN*64 threads
  int i = t>>6, c = t&63;
  const bf16* hr = h + (size_t)i*64;
  float acc = 0.0f;
  #pragma unroll
  for(int k=0;k<64;k++) acc = fmaf(b2f(hr[k]), Ws[k*64+c], acc);
  s[t] = f2b(acc * dinv[i]);
  agg[t] = 0.0f;
}

// one wave per edge, lane = channel
__global__ void k_scatter(const int* __restrict__ src, const int* __restrict__ dst,
                          const bf16* __restrict__ s, float* __restrict__ agg){
  int t = blockIdx.x*256 + threadIdx.x;   // grid exactly NE*64 threads
  int e = t>>6, c = t&63;
  float v = b2f(s[(size_t)src[e]*64 + c]);
  atomicAdd(&agg[(size_t)dst[e]*64 + c], v);
}

// h = relu(dinv*(agg + s) + b)   (self-loop = +s)
__global__ void k_finalize(const float* __restrict__ agg, const bf16* __restrict__ s,
                           const float* __restrict__ dinv, const float* __restrict__ b,
                           bf16* __restrict__ h){
  int t = blockIdx.x*256 + threadIdx.x;
  int i = t>>6, c = t&63;
  float v = dinv[i]*(agg[t] + b2f(s[t])) + b[c];
  h[t] = f2b(fmaxf(v, 0.0f));
}

// fused fc1 (64->128, relu) + fc2 (128->32): 2 nodes per 256-thread block
__global__ void k_fc_fused(const bf16* __restrict__ h, const float* __restrict__ Wc,
                           const int* __restrict__ flag, void* __restrict__ outv){
  __shared__ float W1s[64*128];   // 32 KB
  __shared__ float W2s[128*32];   // 16 KB
  __shared__ float hs[2][64];
  __shared__ float hf[2][128];
  int tid = threadIdx.x;
  for(int j=tid; j<64*128; j+=256) W1s[j] = Wc[FW1F+j];
  for(int j=tid; j<128*32; j+=256) W2s[j] = Wc[FW2F+j];
  int base = blockIdx.x*2;  // grid = NN/2
  if(tid < 128) hs[tid>>6][tid&63] = b2f(h[(size_t)base*64 + tid]);
  __syncthreads();
  int nl = tid>>7, j = tid&127;
  float acc = Wc[FB1F+j];
  #pragma unroll
  for(int k=0;k<64;k++) acc = fmaf(hs[nl][k], W1s[k*128+j], acc);
  hf[nl][j] = fmaxf(acc, 0.0f);
  __syncthreads();
  if(tid < 64){
    int nl2 = tid>>5, c = tid&31;
    float a2 = Wc[FB2F+c];
    #pragma unroll
    for(int k=0;k<128;k++) a2 = fmaf(hf[nl2][k], W2s[k*32+c], a2);
    size_t oi = (size_t)(base+nl2)*32 + c;
    if(*flag) ((float*)outv)[oi] = a2;
    else      ((bf16*)outv)[oi]  = f2b(a2);
  }
}

extern "C" void kernel_launch(void* const* d_in, const int* in_sizes, int n_in,
                              void* d_out, int out_size, void* d_ws, size_t ws_size,
                              hipStream_t stream){
  const void* x   = d_in[0];
  const int*  ei  = (const int*)d_in[1];
  const int* srcI = ei;        // edge_index[0]
  const int* dstI = ei + NE;   // edge_index[1]

  // workspace layout
  char* base = (char*)d_ws;
  int*   flag = (int*)base;                               // 16 B
  float* Wc   = (float*)(base + 16);                      // WTOT f32 (~84 KB)
  float* dinv = (float*)(base + 16 + 84096);              // NN f32
  float* agg  = (float*)(base + 16 + 84096 + 400128);     // NN*64 f32 (25.6 MB)
  bf16*  s    = (bf16*)((char*)agg + (size_t)NN*64*4);    // NN*64 bf16 (12.8 MB)
  bf16*  h    = (bf16*)((char*)s   + (size_t)NN*64*2);    // NN*64 bf16 (12.8 MB)
  // total ~51.7 MB

  k_sniff<<<1, 1024, 0, stream>>>((const unsigned short*)x, flag);
  k_convert_w<<<1, 256, 0, stream>>>(d_in[2], d_in[3], d_in[4], d_in[5], d_in[6],
                                     d_in[7], d_in[8], d_in[9], d_in[10], d_in[11],
                                     flag, Wc);

  k_deg_init<<<(NN+255)/256, 256, 0, stream>>>(dinv);
  k_deg_acc <<<(NE+255)/256, 256, 0, stream>>>(dstI, dinv);
  k_dinv    <<<(NN+255)/256, 256, 0, stream>>>(dinv);

  // layer 1 (2 -> 64)
  k_transform1<<<NN*64/256, 256, 0, stream>>>(x, Wc+W1F, flag, dinv, s, agg);
  k_scatter   <<<NE*64/256, 256, 0, stream>>>(srcI, dstI, s, agg);
  k_finalize  <<<NN*64/256, 256, 0, stream>>>(agg, s, dinv, Wc+B1F, h);

  // layer 2 (64 -> 64)
  k_transform64<<<NN*64/256, 256, 0, stream>>>(h, Wc+W2F, dinv, s, agg);
  k_scatter    <<<NE*64/256, 256, 0, stream>>>(srcI, dstI, s, agg);
  k_finalize   <<<NN*64/256, 256, 0, stream>>>(agg, s, dinv, Wc+B2F, h);

  // layer 3 (64 -> 64)
  k_transform64<<<NN*64/256, 256, 0, stream>>>(h, Wc+W3F, dinv, s, agg);
  k_scatter    <<<NE*64/256, 256, 0, stream>>>(srcI, dstI, s, agg);
  k_finalize   <<<NN*64/256, 256, 0, stream>>>(agg, s, dinv, Wc+B3F, h);

  // fused fc1+fc2
  k_fc_fused<<<NN/2, 256, 0, stream>>>(h, Wc, flag, d_out);
}

// Round 4
// 1396.963 us; speedup vs baseline: 1.3906x; 1.3906x over previous
//
#include <hip/hip_runtime.h>
#include <hip/hip_bf16.h>

#define NN 100000
#define NE 1600000

using bf16 = __hip_bfloat16;
static __device__ __forceinline__ float b2f(bf16 v){ return __bfloat162float(v); }
static __device__ __forceinline__ bf16 f2b(float v){ return __float2bfloat16(v); }

// canonical f32 weight-pool offsets (floats)
#define W1F   0
#define B1F   128
#define W2F   192
#define B2F   4288
#define W3F   4352
#define B3F   8448
#define FW1F  8512
#define FB1F  16704
#define FW2F  16832
#define FB2F  20928
#define WTOT  20960

// ---- dtype sniff: even ushort slots of f32 storage are low-mantissa bits ->
// exponent-field 0xFF/0x00 appears ~0.8% of the time; true bf16 N(0,1) never.
__global__ void k_sniff(const unsigned short* __restrict__ xr, int* flag){
  __shared__ int found;
  if(threadIdx.x==0) found = 0;
  __syncthreads();
  int loc = 0;
  for(int i=threadIdx.x*2; i<200000; i+=2048){
    unsigned e = (xr[i]>>7)&0xFF;
    if(e==0xFFu || e==0u) loc = 1;
  }
  if(loc) found = 1;            // benign same-value race
  __syncthreads();
  if(threadIdx.x==0) *flag = found;   // 1 = f32 storage, 0 = bf16 storage
}

// convert all weights/biases into canonical f32 pool
__global__ void k_convert_w(const void* p0,const void* p1,const void* p2,const void* p3,
                            const void* p4,const void* p5,const void* p6,const void* p7,
                            const void* p8,const void* p9,
                            const int* __restrict__ flag, float* __restrict__ Wc){
  const void* ps[10] = {p0,p1,p2,p3,p4,p5,p6,p7,p8,p9};
  const int off[11] = {W1F,B1F,W2F,B2F,W3F,B3F,FW1F,FB1F,FW2F,FB2F,WTOT};
  int f = *flag;
  for(int t=threadIdx.x; t<WTOT; t+=256){
    int seg = 0;
    while(off[seg+1] <= t) seg++;
    int j = t - off[seg];
    Wc[t] = f ? ((const float*)ps[seg])[j] : b2f(((const bf16*)ps[seg])[j]);
  }
}

// ---------------- CSR build ----------------
__global__ void k_zero(int* p, int n){
  int i = blockIdx.x*256 + threadIdx.x;
  if(i < n) p[i] = 0;
}
__global__ void k_count(const int* __restrict__ dst, int* __restrict__ degc){
  int e = blockIdx.x*256 + threadIdx.x;
  if(e < NE) atomicAdd(&degc[dst[e]], 1);
}
// two-level inclusive scan over degc (NN elems, 1024/block, 98 blocks)
#define NBLK 98
__global__ void k_scan1(const int* __restrict__ degc, int* __restrict__ tmp,
                        int* __restrict__ bsum){
  __shared__ int sh[1024];
  int gi = blockIdx.x*1024 + threadIdx.x;
  int v = (gi < NN) ? degc[gi] : 0;
  sh[threadIdx.x] = v; __syncthreads();
  for(int off=1; off<1024; off<<=1){
    int t = (threadIdx.x>=off) ? sh[threadIdx.x-off] : 0;
    __syncthreads();
    sh[threadIdx.x] += t;
    __syncthreads();
  }
  if(gi < NN) tmp[gi] = sh[threadIdx.x];
  if(threadIdx.x == 1023) bsum[blockIdx.x] = sh[1023];
}
__global__ void k_scan2(const int* __restrict__ bsum, int* __restrict__ boff){
  __shared__ int sh[128];
  int v = (threadIdx.x < NBLK) ? bsum[threadIdx.x] : 0;
  sh[threadIdx.x] = v; __syncthreads();
  for(int off=1; off<128; off<<=1){
    int t = (threadIdx.x>=off) ? sh[threadIdx.x-off] : 0;
    __syncthreads();
    sh[threadIdx.x] += t;
    __syncthreads();
  }
  boff[threadIdx.x] = sh[threadIdx.x] - v;   // exclusive
}
__global__ void k_scan3(const int* __restrict__ tmp, const int* __restrict__ boff,
                        const int* __restrict__ degc, int* __restrict__ rowptr,
                        int* __restrict__ cursor, float* __restrict__ dinv){
  int i = blockIdx.x*256 + threadIdx.x;
  if(i < NN){
    int incl = tmp[i] + boff[i>>10];
    rowptr[i+1] = incl;
    cursor[i]   = incl - degc[i];     // exclusive start
    if(i == 0) rowptr[0] = 0;
    dinv[i] = rsqrtf((float)(degc[i] + 1));   // +1 self-loop
  }
}
__global__ void k_place(const int* __restrict__ src, const int* __restrict__ dst,
                        int* __restrict__ cursor, int* __restrict__ srcS){
  int e = blockIdx.x*256 + threadIdx.x;
  if(e < NE){
    int pos = atomicAdd(&cursor[dst[e]], 1);
    srcS[pos] = src[e];
  }
}

// ---------------- layers ----------------
// layer 1: s = dinv * (x @ W1)  (x is N x 2)
__global__ void k_transform1(const void* __restrict__ xv, const float* __restrict__ W1c,
                             const int* __restrict__ flag, const float* __restrict__ dinv,
                             bf16* __restrict__ s){
  int t = blockIdx.x*256 + threadIdx.x;   // grid exactly NN*64 threads
  int i = t>>6, c = t&63;
  float x0, x1;
  if(*flag){ const float* xp=(const float*)xv; x0=xp[2*i]; x1=xp[2*i+1]; }
  else     { const bf16*  xp=(const bf16*)xv;  x0=b2f(xp[2*i]); x1=b2f(xp[2*i+1]); }
  float v = x0*W1c[c] + x1*W1c[64+c];
  s[t] = f2b(v * dinv[i]);
}

// 64->64 transform, persistent blocks: s = dinv * (h @ W)
__global__ void k_transform64(const bf16* __restrict__ h, const float* __restrict__ W,
                              const float* __restrict__ dinv, bf16* __restrict__ s){
  __shared__ float Ws[64*64];
  for(int j=threadIdx.x; j<64*64; j+=256) Ws[j] = W[j];
  __syncthreads();
  int c = threadIdx.x & 63, w = threadIdx.x >> 6;
  for(int g = blockIdx.x; g < NN/4; g += 2048){
    int i = g*4 + w;
    const bf16* hr = h + (size_t)i*64;
    float acc = 0.0f;
    #pragma unroll
    for(int k=0;k<64;k++) acc = fmaf(b2f(hr[k]), Ws[k*64+c], acc);
    s[(size_t)i*64+c] = f2b(acc * dinv[i]);
  }
}

// CSR aggregate + finalize: h = relu(dinv*(sum_{in-edges} s[src] + s[i]) + b)
__global__ void k_aggregate(const int* __restrict__ rowptr, const int* __restrict__ srcS,
                            const bf16* __restrict__ s, const float* __restrict__ dinv,
                            const float* __restrict__ b, bf16* __restrict__ h){
  int t = blockIdx.x*256 + threadIdx.x;   // grid NN*64/256
  int i = t>>6, c = t&63;
  int beg = rowptr[i], end = rowptr[i+1];
  float acc = b2f(s[(size_t)i*64 + c]);   // self-loop
  for(int p=beg; p<end; p++){
    int sj = srcS[p];                     // wave-uniform
    acc += b2f(s[(size_t)sj*64 + c]);     // coalesced 128B gather
  }
  float v = dinv[i]*acc + b[c];
  h[(size_t)i*64+c] = f2b(fmaxf(v, 0.0f));
}

// fused fc1 (64->128, relu) + fc2 (128->32), persistent blocks, 4 nodes/iter
__global__ void k_fc_fused(const bf16* __restrict__ h, const float* __restrict__ Wc,
                           const int* __restrict__ flag, void* __restrict__ outv){
  __shared__ float W1s[64*128];   // 32 KB
  __shared__ float W2s[128*32];   // 16 KB
  __shared__ float hs[4][64];
  __shared__ float hf[4][128];
  int tid = threadIdx.x;
  for(int j=tid; j<64*128; j+=256) W1s[j] = Wc[FW1F+j];
  for(int j=tid; j<128*32; j+=256) W2s[j] = Wc[FW2F+j];
  int f = *flag;
  for(int p = blockIdx.x; p < NN/4; p += 768){
    int base = p*4;
    __syncthreads();                       // protect hs/hf reuse
    hs[tid>>6][tid&63] = b2f(h[(size_t)base*64 + tid]);
    __syncthreads();
    #pragma unroll
    for(int r=0;r<2;r++){
      int idx = tid + r*256;
      int nl = idx>>7, j = idx&127;
      float acc = Wc[FB1F+j];
      #pragma unroll
      for(int k=0;k<64;k++) acc = fmaf(hs[nl][k], W1s[k*128+j], acc);
      hf[nl][j] = fmaxf(acc, 0.0f);
    }
    __syncthreads();
    if(tid < 128){
      int nl = tid>>5, c = tid&31;
      float a2 = Wc[FB2F+c];
      #pragma unroll
      for(int k=0;k<128;k++) a2 = fmaf(hf[nl][k], W2s[k*32+c], a2);
      size_t oi = (size_t)(base+nl)*32 + c;
      if(f) ((float*)outv)[oi] = a2;
      else  ((bf16*)outv)[oi]  = f2b(a2);
    }
  }
}

extern "C" void kernel_launch(void* const* d_in, const int* in_sizes, int n_in,
                              void* d_out, int out_size, void* d_ws, size_t ws_size,
                              hipStream_t stream){
  const void* x   = d_in[0];
  const int*  ei  = (const int*)d_in[1];
  const int* srcI = ei;        // edge_index[0]
  const int* dstI = ei + NE;   // edge_index[1]

  // workspace layout (bytes), all 16B-aligned; total ~34.1 MB
  char* base = (char*)d_ws;
  int*   flag   = (int*)   (base + 0);         // 256
  float* Wc     = (float*) (base + 256);       // 83840 -> ends 84096
  int*   degc   = (int*)   (base + 84480);     // 400000
  int*   tmp    = (int*)   (base + 484608);    // 400000
  int*   bsum   = (int*)   (base + 884736);    // 512
  int*   boff   = (int*)   (base + 885248);    // 512
  int*   rowptr = (int*)   (base + 885760);    // 400004
  int*   cursor = (int*)   (base + 1286144);   // 400000
  float* dinv   = (float*) (base + 1686272);   // 400000
  int*   srcS   = (int*)   (base + 2086400);   // 6400000
  bf16*  s      = (bf16*)  (base + 8486400);   // 12800000
  bf16*  h      = (bf16*)  (base + 21286400);  // 12800000

  k_sniff<<<1, 1024, 0, stream>>>((const unsigned short*)x, flag);
  k_convert_w<<<1, 256, 0, stream>>>(d_in[2], d_in[3], d_in[4], d_in[5], d_in[6],
                                     d_in[7], d_in[8], d_in[9], d_in[10], d_in[11],
                                     flag, Wc);

  // CSR build
  k_zero <<<(NN+255)/256, 256, 0, stream>>>(degc, NN);
  k_count<<<(NE+255)/256, 256, 0, stream>>>(dstI, degc);
  k_scan1<<<NBLK, 1024, 0, stream>>>(degc, tmp, bsum);
  k_scan2<<<1, 128, 0, stream>>>(bsum, boff);
  k_scan3<<<(NN+255)/256, 256, 0, stream>>>(tmp, boff, degc, rowptr, cursor, dinv);
  k_place<<<(NE+255)/256, 256, 0, stream>>>(srcI, dstI, cursor, srcS);

  // layer 1 (2 -> 64)
  k_transform1<<<NN*64/256, 256, 0, stream>>>(x, Wc+W1F, flag, dinv, s);
  k_aggregate <<<NN*64/256, 256, 0, stream>>>(rowptr, srcS, s, dinv, Wc+B1F, h);

  // layer 2 (64 -> 64)
  k_transform64<<<2048, 256, 0, stream>>>(h, Wc+W2F, dinv, s);
  k_aggregate  <<<NN*64/256, 256, 0, stream>>>(rowptr, srcS, s, dinv, Wc+B2F, h);

  // layer 3 (64 -> 64)
  k_transform64<<<2048, 256, 0, stream>>>(h, Wc+W3F, dinv, s);
  k_aggregate  <<<NN*64/256, 256, 0, stream>>>(rowptr, srcS, s, dinv, Wc+B3F, h);

  // fused fc1+fc2
  k_fc_fused<<<768, 256, 0, stream>>>(h, Wc, flag, d_out);
}

// Round 5
// 747.706 us; speedup vs baseline: 2.5982x; 1.8683x over previous
//
#include <hip/hip_runtime.h>
#include <hip/hip_bf16.h>

#define NN 100000
#define NE 1600000

using bf16 = __hip_bfloat16;
typedef unsigned short us8_t __attribute__((ext_vector_type(8)));
static __device__ __forceinline__ float b2f(bf16 v){ return __bfloat162float(v); }
static __device__ __forceinline__ bf16 f2b(float v){ return __float2bfloat16(v); }
static __device__ __forceinline__ float us2f(unsigned short u){
  unsigned x = ((unsigned)u)<<16; float f; __builtin_memcpy(&f,&x,4); return f;
}
static __device__ __forceinline__ unsigned short f2us(float v){
  bf16 b = f2b(v); unsigned short u; __builtin_memcpy(&u,&b,2); return u;
}

// canonical f32 weight-pool offsets (floats)
#define W1F   0
#define B1F   128
#define W2F   192
#define B2F   4288
#define W3F   4352
#define B3F   8448
#define FW1F  8512
#define FB1F  16704
#define FW2F  16832
#define FB2F  20928
#define WTOT  20960

// ---- dtype sniff (f32 vs bf16 storage) ----
__global__ void k_sniff(const unsigned short* __restrict__ xr, int* flag){
  __shared__ int found;
  if(threadIdx.x==0) found = 0;
  __syncthreads();
  int loc = 0;
  for(int i=threadIdx.x*2; i<200000; i+=2048){
    unsigned e = (xr[i]>>7)&0xFF;
    if(e==0xFFu || e==0u) loc = 1;
  }
  if(loc) found = 1;
  __syncthreads();
  if(threadIdx.x==0) *flag = found;   // 1 = f32 storage, 0 = bf16 storage
}

__global__ void k_convert_w(const void* p0,const void* p1,const void* p2,const void* p3,
                            const void* p4,const void* p5,const void* p6,const void* p7,
                            const void* p8,const void* p9,
                            const int* __restrict__ flag, float* __restrict__ Wc){
  const void* ps[10] = {p0,p1,p2,p3,p4,p5,p6,p7,p8,p9};
  const int off[11] = {W1F,B1F,W2F,B2F,W3F,B3F,FW1F,FB1F,FW2F,FB2F,WTOT};
  int f = *flag;
  for(int t=threadIdx.x; t<WTOT; t+=256){
    int seg = 0;
    while(off[seg+1] <= t) seg++;
    int j = t - off[seg];
    Wc[t] = f ? ((const float*)ps[seg])[j] : b2f(((const bf16*)ps[seg])[j]);
  }
}

// ---------------- CSR build ----------------
__global__ void k_zero(int* p, int n){
  int i = blockIdx.x*256 + threadIdx.x;
  if(i < n) p[i] = 0;
}
__global__ void k_count(const int* __restrict__ dst, int* __restrict__ degc){
  int e = blockIdx.x*256 + threadIdx.x;
  if(e < NE) atomicAdd(&degc[dst[e]], 1);
}
#define NBLK 98
__global__ void k_scan1(const int* __restrict__ degc, int* __restrict__ tmp,
                        int* __restrict__ bsum){
  __shared__ int sh[1024];
  int gi = blockIdx.x*1024 + threadIdx.x;
  int v = (gi < NN) ? degc[gi] : 0;
  sh[threadIdx.x] = v; __syncthreads();
  for(int off=1; off<1024; off<<=1){
    int t = (threadIdx.x>=off) ? sh[threadIdx.x-off] : 0;
    __syncthreads();
    sh[threadIdx.x] += t;
    __syncthreads();
  }
  if(gi < NN) tmp[gi] = sh[threadIdx.x];
  if(threadIdx.x == 1023) bsum[blockIdx.x] = sh[1023];
}
__global__ void k_scan2(const int* __restrict__ bsum, int* __restrict__ boff){
  __shared__ int sh[128];
  int v = (threadIdx.x < NBLK) ? bsum[threadIdx.x] : 0;
  sh[threadIdx.x] = v; __syncthreads();
  for(int off=1; off<128; off<<=1){
    int t = (threadIdx.x>=off) ? sh[threadIdx.x-off] : 0;
    __syncthreads();
    sh[threadIdx.x] += t;
    __syncthreads();
  }
  boff[threadIdx.x] = sh[threadIdx.x] - v;   // exclusive
}
__global__ void k_scan3(const int* __restrict__ tmp, const int* __restrict__ boff,
                        const int* __restrict__ degc, int* __restrict__ rowptr,
                        int* __restrict__ cursor, float* __restrict__ dinv){
  int i = blockIdx.x*256 + threadIdx.x;
  if(i < NN){
    int incl = tmp[i] + boff[i>>10];
    rowptr[i+1] = incl;
    cursor[i]   = incl - degc[i];
    if(i == 0) rowptr[0] = 0;
    dinv[i] = rsqrtf((float)(degc[i] + 1));   // +1 self-loop
  }
}
__global__ void k_place(const int* __restrict__ src, const int* __restrict__ dst,
                        int* __restrict__ cursor, int* __restrict__ srcS){
  int e = blockIdx.x*256 + threadIdx.x;
  if(e < NE){
    int pos = atomicAdd(&cursor[dst[e]], 1);
    srcS[pos] = src[e];
  }
}

// ---------------- layers ----------------
// layer 1: s = dinv * (x @ W1); thread = (node, 8 channels), 16B stores
__global__ void k_transform1(const void* __restrict__ xv, const float* __restrict__ Wc,
                             const int* __restrict__ flag, const float* __restrict__ dinv,
                             bf16* __restrict__ s){
  __shared__ float W1s[128];
  if(threadIdx.x < 128) W1s[threadIdx.x] = Wc[W1F + threadIdx.x];
  __syncthreads();
  int t = blockIdx.x*256 + threadIdx.x;   // grid NN*8 threads
  int i = t>>3, g = t&7;
  float x0, x1;
  if(*flag){ const float2 p = ((const float2*)xv)[i]; x0=p.x; x1=p.y; }
  else     { const bf16*  xp=(const bf16*)xv; x0=b2f(xp[2*i]); x1=b2f(xp[2*i+1]); }
  float dv = dinv[i];
  us8_t o;
  #pragma unroll
  for(int j=0;j<8;j++){
    int c = g*8+j;
    o[j] = f2us((x0*W1s[c] + x1*W1s[64+c]) * dv);
  }
  *(us8_t*)((unsigned short*)s + (size_t)i*64 + g*8) = o;
}

// 64->64 transform: LDS-tiled 64x64 GEMM, 4x4 register tile/thread.
// s = dinv * (h @ W).  grid = ceil(NN/64) blocks of 256.
__global__ void __launch_bounds__(256) k_transform64(
    const bf16* __restrict__ h, const float* __restrict__ W,
    const float* __restrict__ dinv, bf16* __restrict__ s){
  __shared__ float Ws[64*64];     // 16 KB
  __shared__ float hs[64][68];    // 17.4 KB, pad 68 breaks bank collisions
  __shared__ float dl[64];
  int tid = threadIdx.x;
  for(int j=tid; j<4096; j+=256) Ws[j] = W[j];
  int row0 = blockIdx.x*64;
  if(tid < 64){ int r = row0+tid; dl[tid] = (r<NN)? dinv[r] : 0.0f; }
  // stage h tile: 512 chunks of 8 bf16 (16B vector loads, fully coalesced)
  for(int ch = tid; ch < 512; ch += 256){
    int r = ch>>3, c8 = (ch&7)*8;
    int gr = row0 + r;
    float f[8];
    if(gr < NN){
      us8_t v = *(const us8_t*)((const unsigned short*)h + (size_t)gr*64 + c8);
      #pragma unroll
      for(int j=0;j<8;j++) f[j] = us2f(v[j]);
    } else {
      #pragma unroll
      for(int j=0;j<8;j++) f[j] = 0.0f;
    }
    *(float4*)&hs[r][c8]   = make_float4(f[0],f[1],f[2],f[3]);
    *(float4*)&hs[r][c8+4] = make_float4(f[4],f[5],f[6],f[7]);
  }
  __syncthreads();
  int ty = tid>>4, tx = tid&15;     // rows ty*4..+3, cols tx*4..+3
  float acc[4][4] = {{0}};
  #pragma unroll 8
  for(int k=0;k<64;k++){
    float4 b4 = *(const float4*)&Ws[k*64 + tx*4];   // 2-way bank alias: free
    float a0 = hs[ty*4+0][k];                        // broadcast reads
    float a1 = hs[ty*4+1][k];
    float a2 = hs[ty*4+2][k];
    float a3 = hs[ty*4+3][k];
    acc[0][0] = fmaf(a0,b4.x,acc[0][0]); acc[0][1] = fmaf(a0,b4.y,acc[0][1]);
    acc[0][2] = fmaf(a0,b4.z,acc[0][2]); acc[0][3] = fmaf(a0,b4.w,acc[0][3]);
    acc[1][0] = fmaf(a1,b4.x,acc[1][0]); acc[1][1] = fmaf(a1,b4.y,acc[1][1]);
    acc[1][2] = fmaf(a1,b4.z,acc[1][2]); acc[1][3] = fmaf(a1,b4.w,acc[1][3]);
    acc[2][0] = fmaf(a2,b4.x,acc[2][0]); acc[2][1] = fmaf(a2,b4.y,acc[2][1]);
    acc[2][2] = fmaf(a2,b4.z,acc[2][2]); acc[2][3] = fmaf(a2,b4.w,acc[2][3]);
    acc[3][0] = fmaf(a3,b4.x,acc[3][0]); acc[3][1] = fmaf(a3,b4.y,acc[3][1]);
    acc[3][2] = fmaf(a3,b4.z,acc[3][2]); acc[3][3] = fmaf(a3,b4.w,acc[3][3]);
  }
  // store: per rr, pack 4 bf16 -> 8B; 4x128B full-line segments per inst
  #pragma unroll
  for(int rr=0; rr<4; rr++){
    int r = row0 + ty*4 + rr;
    if(r < NN){
      float dv = dl[ty*4+rr];
      unsigned lo = f2us(acc[rr][0]*dv) | ((unsigned)f2us(acc[rr][1]*dv) << 16);
      unsigned hi = f2us(acc[rr][2]*dv) | ((unsigned)f2us(acc[rr][3]*dv) << 16);
      uint2 o; o.x = lo; o.y = hi;
      *(uint2*)((unsigned short*)s + (size_t)r*64 + tx*4) = o;
    }
  }
}

// CSR aggregate + finalize: h = relu(dinv*(sum s[src] + s[i]) + b)
// wave per node, lane = channel; 4-deep unroll for MLP; packed 16B stores
__global__ void k_aggregate(const int* __restrict__ rowptr, const int* __restrict__ srcS,
                            const bf16* __restrict__ s, const float* __restrict__ dinv,
                            const float* __restrict__ b, bf16* __restrict__ h){
  int t = blockIdx.x*256 + threadIdx.x;   // grid NN*64/256
  int i = t>>6, c = t&63;
  int beg = rowptr[i], end = rowptr[i+1];
  float a0 = b2f(s[(size_t)i*64 + c]);    // self-loop
  float a1 = 0.f, a2 = 0.f, a3 = 0.f;
  int p = beg;
  for(; p+4 <= end; p += 4){
    int s0 = srcS[p], s1 = srcS[p+1], s2 = srcS[p+2], s3 = srcS[p+3];
    a0 += b2f(s[(size_t)s0*64 + c]);
    a1 += b2f(s[(size_t)s1*64 + c]);
    a2 += b2f(s[(size_t)s2*64 + c]);
    a3 += b2f(s[(size_t)s3*64 + c]);
  }
  for(; p < end; p++) a0 += b2f(s[(size_t)srcS[p]*64 + c]);
  float v = fmaxf(dinv[i]*((a0+a1)+(a2+a3)) + b[c], 0.0f);
  // pack: lanes 0..7 collect 8 channels each via shfl -> one 16B store
  int lane = threadIdx.x & 63;
  int my = (int)f2us(v);
  unsigned short g[8];
  #pragma unroll
  for(int j=0;j<8;j++) g[j] = (unsigned short)__shfl(my, lane*8 + j, 64);
  if(lane < 8){
    us8_t o;
    #pragma unroll
    for(int j=0;j<8;j++) o[j] = g[j];
    *(us8_t*)((unsigned short*)h + (size_t)i*64 + lane*8) = o;
  }
}

// fused fc1 (64->128, relu) + fc2 (128->32), persistent blocks
__global__ void k_fc_fused(const bf16* __restrict__ h, const float* __restrict__ Wc,
                           const int* __restrict__ flag, void* __restrict__ outv){
  __shared__ float W1s[64*128];   // 32 KB
  __shared__ float W2s[128*32];   // 16 KB
  __shared__ float hs[4][64];
  __shared__ float hf[4][128];
  int tid = threadIdx.x;
  for(int j=tid; j<64*128; j+=256) W1s[j] = Wc[FW1F+j];
  for(int j=tid; j<128*32; j+=256) W2s[j] = Wc[FW2F+j];
  int f = *flag;
  for(int p = blockIdx.x; p < NN/4; p += 768){
    int base = p*4;
    __syncthreads();
    hs[tid>>6][tid&63] = b2f(h[(size_t)base*64 + tid]);
    __syncthreads();
    #pragma unroll
    for(int r=0;r<2;r++){
      int idx = tid + r*256;
      int nl = idx>>7, j = idx&127;
      float acc = Wc[FB1F+j];
      #pragma unroll
      for(int k=0;k<64;k++) acc = fmaf(hs[nl][k], W1s[k*128+j], acc);
      hf[nl][j] = fmaxf(acc, 0.0f);
    }
    __syncthreads();
    if(tid < 128){
      int nl = tid>>5, c = tid&31;
      float a2 = Wc[FB2F+c];
      #pragma unroll
      for(int k=0;k<128;k++) a2 = fmaf(hf[nl][k], W2s[k*32+c], a2);
      size_t oi = (size_t)(base+nl)*32 + c;
      if(f) ((float*)outv)[oi] = a2;
      else  ((bf16*)outv)[oi]  = f2b(a2);
    }
  }
}

extern "C" void kernel_launch(void* const* d_in, const int* in_sizes, int n_in,
                              void* d_out, int out_size, void* d_ws, size_t ws_size,
                              hipStream_t stream){
  const void* x   = d_in[0];
  const int*  ei  = (const int*)d_in[1];
  const int* srcI = ei;        // edge_index[0]
  const int* dstI = ei + NE;   // edge_index[1]

  // workspace layout (bytes); total ~34.1 MB
  char* base = (char*)d_ws;
  int*   flag   = (int*)   (base + 0);         // 256
  float* Wc     = (float*) (base + 256);       // 83840
  int*   degc   = (int*)   (base + 84480);     // 400000
  int*   tmp    = (int*)   (base + 484608);    // 400000
  int*   bsum   = (int*)   (base + 884736);    // 512
  int*   boff   = (int*)   (base + 885248);    // 512
  int*   rowptr = (int*)   (base + 885760);    // 400004
  int*   cursor = (int*)   (base + 1286144);   // 400000
  float* dinv   = (float*) (base + 1686272);   // 400000
  int*   srcS   = (int*)   (base + 2086400);   // 6400000
  bf16*  s      = (bf16*)  (base + 8486400);   // 12800000
  bf16*  h      = (bf16*)  (base + 21286400);  // 12800000

  k_sniff<<<1, 1024, 0, stream>>>((const unsigned short*)x, flag);
  k_convert_w<<<1, 256, 0, stream>>>(d_in[2], d_in[3], d_in[4], d_in[5], d_in[6],
                                     d_in[7], d_in[8], d_in[9], d_in[10], d_in[11],
                                     flag, Wc);

  // CSR build
  k_zero <<<(NN+255)/256, 256, 0, stream>>>(degc, NN);
  k_count<<<(NE+255)/256, 256, 0, stream>>>(dstI, degc);
  k_scan1<<<NBLK, 1024, 0, stream>>>(degc, tmp, bsum);
  k_scan2<<<1, 128, 0, stream>>>(bsum, boff);
  k_scan3<<<(NN+255)/256, 256, 0, stream>>>(tmp, boff, degc, rowptr, cursor, dinv);
  k_place<<<(NE+255)/256, 256, 0, stream>>>(srcI, dstI, cursor, srcS);

  // layer 1 (2 -> 64)
  k_transform1<<<NN*8/256, 256, 0, stream>>>(x, Wc, flag, dinv, s);
  k_aggregate <<<NN*64/256, 256, 0, stream>>>(rowptr, srcS, s, dinv, Wc+B1F, h);

  // layer 2 (64 -> 64)
  k_transform64<<<(NN+63)/64, 256, 0, stream>>>(h, Wc+W2F, dinv, s);
  k_aggregate  <<<NN*64/256, 256, 0, stream>>>(rowptr, srcS, s, dinv, Wc+B2F, h);

  // layer 3 (64 -> 64)
  k_transform64<<<(NN+63)/64, 256, 0, stream>>>(h, Wc+W3F, dinv, s);
  k_aggregate  <<<NN*64/256, 256, 0, stream>>>(rowptr, srcS, s, dinv, Wc+B3F, h);

  // fused fc1+fc2
  k_fc_fused<<<768, 256, 0, stream>>>(h, Wc, flag, d_out);
}

// Round 6
// 618.547 us; speedup vs baseline: 3.1407x; 1.2088x over previous
//
#include <hip/hip_runtime.h>
#include <hip/hip_bf16.h>

#define NN 100000
#define NE 1600000

using bf16 = __hip_bfloat16;
typedef unsigned short us8_t __attribute__((ext_vector_type(8)));
static __device__ __forceinline__ float b2f(bf16 v){ return __bfloat162float(v); }
static __device__ __forceinline__ bf16 f2b(float v){ return __float2bfloat16(v); }
static __device__ __forceinline__ float us2f(unsigned short u){
  unsigned x = ((unsigned)u)<<16; float f; __builtin_memcpy(&f,&x,4); return f;
}
static __device__ __forceinline__ unsigned short f2us(float v){
  bf16 b = f2b(v); unsigned short u; __builtin_memcpy(&u,&b,2); return u;
}

// canonical f32 weight-pool offsets (floats)
#define W1F   0
#define B1F   128
#define W2F   192
#define B2F   4288
#define W3F   4352
#define B3F   8448
#define FW1F  8512
#define FB1F  16704
#define FW2F  16832
#define FB2F  20928
#define WTOT  20960

// ---- dtype sniff (f32 vs bf16 storage) ----
__global__ void k_sniff(const unsigned short* __restrict__ xr, int* flag){
  __shared__ int found;
  if(threadIdx.x==0) found = 0;
  __syncthreads();
  int loc = 0;
  for(int i=threadIdx.x*2; i<200000; i+=2048){
    unsigned e = (xr[i]>>7)&0xFF;
    if(e==0xFFu || e==0u) loc = 1;
  }
  if(loc) found = 1;
  __syncthreads();
  if(threadIdx.x==0) *flag = found;   // 1 = f32 storage, 0 = bf16 storage
}

__global__ void k_convert_w(const void* p0,const void* p1,const void* p2,const void* p3,
                            const void* p4,const void* p5,const void* p6,const void* p7,
                            const void* p8,const void* p9,
                            const int* __restrict__ flag, float* __restrict__ Wc){
  const void* ps[10] = {p0,p1,p2,p3,p4,p5,p6,p7,p8,p9};
  const int off[11] = {W1F,B1F,W2F,B2F,W3F,B3F,FW1F,FB1F,FW2F,FB2F,WTOT};
  int f = *flag;
  for(int t=threadIdx.x; t<WTOT; t+=256){
    int seg = 0;
    while(off[seg+1] <= t) seg++;
    int j = t - off[seg];
    Wc[t] = f ? ((const float*)ps[seg])[j] : b2f(((const bf16*)ps[seg])[j]);
  }
}

// ---------------- CSR build ----------------
__global__ void k_zero(int* p, int n){
  int i = blockIdx.x*256 + threadIdx.x;
  if(i < n) p[i] = 0;
}
__global__ void k_count(const int* __restrict__ dst, int* __restrict__ degc){
  int e = blockIdx.x*256 + threadIdx.x;
  if(e < NE) atomicAdd(&degc[dst[e]], 1);
}
#define NBLK 98
__global__ void k_scan1(const int* __restrict__ degc, int* __restrict__ tmp,
                        int* __restrict__ bsum){
  __shared__ int sh[1024];
  int gi = blockIdx.x*1024 + threadIdx.x;
  int v = (gi < NN) ? degc[gi] : 0;
  sh[threadIdx.x] = v; __syncthreads();
  for(int off=1; off<1024; off<<=1){
    int t = (threadIdx.x>=off) ? sh[threadIdx.x-off] : 0;
    __syncthreads();
    sh[threadIdx.x] += t;
    __syncthreads();
  }
  if(gi < NN) tmp[gi] = sh[threadIdx.x];
  if(threadIdx.x == 1023) bsum[blockIdx.x] = sh[1023];
}
__global__ void k_scan2(const int* __restrict__ bsum, int* __restrict__ boff){
  __shared__ int sh[128];
  int v = (threadIdx.x < NBLK) ? bsum[threadIdx.x] : 0;
  sh[threadIdx.x] = v; __syncthreads();
  for(int off=1; off<128; off<<=1){
    int t = (threadIdx.x>=off) ? sh[threadIdx.x-off] : 0;
    __syncthreads();
    sh[threadIdx.x] += t;
    __syncthreads();
  }
  boff[threadIdx.x] = sh[threadIdx.x] - v;   // exclusive
}
__global__ void k_scan3(const int* __restrict__ tmp, const int* __restrict__ boff,
                        const int* __restrict__ degc, int* __restrict__ rowptr,
                        int* __restrict__ cursor, float* __restrict__ dinv){
  int i = blockIdx.x*256 + threadIdx.x;
  if(i < NN){
    int incl = tmp[i] + boff[i>>10];
    rowptr[i+1] = incl;
    cursor[i]   = incl - degc[i];
    if(i == 0) rowptr[0] = 0;
    dinv[i] = rsqrtf((float)(degc[i] + 1));   // +1 self-loop
  }
}
__global__ void k_place(const int* __restrict__ src, const int* __restrict__ dst,
                        int* __restrict__ cursor, int* __restrict__ srcS){
  int e = blockIdx.x*256 + threadIdx.x;
  if(e < NE){
    int pos = atomicAdd(&cursor[dst[e]], 1);
    srcS[pos] = src[e];
  }
}

// ---------------- layer 1 (propagate-then-transform; X has only 2 channels) ----------------
// xd[i] = dinv[i] * x[i]   (float2)
__global__ void k_xd(const void* __restrict__ xv, const int* __restrict__ flag,
                     const float* __restrict__ dinv, float2* __restrict__ xd){
  int i = blockIdx.x*256 + threadIdx.x;
  if(i >= NN) return;
  float x0, x1;
  if(*flag){ float2 p = ((const float2*)xv)[i]; x0=p.x; x1=p.y; }
  else     { const bf16* xp=(const bf16*)xv; x0=b2f(xp[2*i]); x1=b2f(xp[2*i+1]); }
  float d = dinv[i];
  xd[i] = make_float2(x0*d, x1*d);
}
// y[i] = sum_{src in in(i)} xd[src] + xd[i]   (8B random gathers, L2-resident)
__global__ void k_prop_x(const int* __restrict__ rowptr, const int* __restrict__ srcS,
                         const float2* __restrict__ xd, float2* __restrict__ y){
  int i = blockIdx.x*256 + threadIdx.x;
  if(i >= NN) return;
  int beg = rowptr[i], end = rowptr[i+1];
  float2 self = xd[i];
  float ax0 = self.x, ay0 = self.y;
  float ax1=0,ay1=0, ax2=0,ay2=0, ax3=0,ay3=0;
  int p = beg;
  for(; p+4 <= end; p += 4){
    int s0=srcS[p], s1=srcS[p+1], s2=srcS[p+2], s3=srcS[p+3];
    float2 v0=xd[s0], v1=xd[s1], v2=xd[s2], v3=xd[s3];
    ax0+=v0.x; ay0+=v0.y; ax1+=v1.x; ay1+=v1.y;
    ax2+=v2.x; ay2+=v2.y; ax3+=v3.x; ay3+=v3.y;
  }
  for(; p<end; p++){ float2 v=xd[srcS[p]]; ax0+=v.x; ay0+=v.y; }
  y[i] = make_float2((ax0+ax1)+(ax2+ax3), (ay0+ay1)+(ay2+ay3));
}
// h1 = relu(dinv * (y @ W1) + b1); thread = (node, 8 channels)
__global__ void k_transform1b(const float2* __restrict__ y, const float* __restrict__ Wc,
                              const float* __restrict__ dinv, bf16* __restrict__ h){
  __shared__ float W1s[128];
  __shared__ float bs[64];
  if(threadIdx.x < 128) W1s[threadIdx.x] = Wc[W1F + threadIdx.x];
  if(threadIdx.x < 64)  bs[threadIdx.x]  = Wc[B1F + threadIdx.x];
  __syncthreads();
  int t = blockIdx.x*256 + threadIdx.x;   // grid NN*8 threads
  int i = t>>3, g = t&7;
  float2 yv = y[i];
  float d = dinv[i];
  us8_t o;
  #pragma unroll
  for(int j=0;j<8;j++){
    int c = g*8+j;
    o[j] = f2us(fmaxf(d*(yv.x*W1s[c] + yv.y*W1s[64+c]) + bs[c], 0.0f));
  }
  *(us8_t*)((unsigned short*)h + (size_t)i*64 + g*8) = o;
}

// ---------------- 64->64 transform (LDS-tiled GEMM, 4x4 tile/thread) ----------------
__global__ void __launch_bounds__(256) k_transform64(
    const bf16* __restrict__ h, const float* __restrict__ W,
    const float* __restrict__ dinv, bf16* __restrict__ s){
  __shared__ float Ws[64*64];
  __shared__ float hs[64][68];
  __shared__ float dl[64];
  int tid = threadIdx.x;
  for(int j=tid; j<4096; j+=256) Ws[j] = W[j];
  int row0 = blockIdx.x*64;
  if(tid < 64){ int r = row0+tid; dl[tid] = (r<NN)? dinv[r] : 0.0f; }
  for(int ch = tid; ch < 512; ch += 256){
    int r = ch>>3, c8 = (ch&7)*8;
    int gr = row0 + r;
    float f[8];
    if(gr < NN){
      us8_t v = *(const us8_t*)((const unsigned short*)h + (size_t)gr*64 + c8);
      #pragma unroll
      for(int j=0;j<8;j++) f[j] = us2f(v[j]);
    } else {
      #pragma unroll
      for(int j=0;j<8;j++) f[j] = 0.0f;
    }
    *(float4*)&hs[r][c8]   = make_float4(f[0],f[1],f[2],f[3]);
    *(float4*)&hs[r][c8+4] = make_float4(f[4],f[5],f[6],f[7]);
  }
  __syncthreads();
  int ty = tid>>4, tx = tid&15;
  float acc[4][4] = {{0}};
  #pragma unroll 8
  for(int k=0;k<64;k++){
    float4 b4 = *(const float4*)&Ws[k*64 + tx*4];
    float a0 = hs[ty*4+0][k];
    float a1 = hs[ty*4+1][k];
    float a2 = hs[ty*4+2][k];
    float a3 = hs[ty*4+3][k];
    acc[0][0] = fmaf(a0,b4.x,acc[0][0]); acc[0][1] = fmaf(a0,b4.y,acc[0][1]);
    acc[0][2] = fmaf(a0,b4.z,acc[0][2]); acc[0][3] = fmaf(a0,b4.w,acc[0][3]);
    acc[1][0] = fmaf(a1,b4.x,acc[1][0]); acc[1][1] = fmaf(a1,b4.y,acc[1][1]);
    acc[1][2] = fmaf(a1,b4.z,acc[1][2]); acc[1][3] = fmaf(a1,b4.w,acc[1][3]);
    acc[2][0] = fmaf(a2,b4.x,acc[2][0]); acc[2][1] = fmaf(a2,b4.y,acc[2][1]);
    acc[2][2] = fmaf(a2,b4.z,acc[2][2]); acc[2][3] = fmaf(a2,b4.w,acc[2][3]);
    acc[3][0] = fmaf(a3,b4.x,acc[3][0]); acc[3][1] = fmaf(a3,b4.y,acc[3][1]);
    acc[3][2] = fmaf(a3,b4.z,acc[3][2]); acc[3][3] = fmaf(a3,b4.w,acc[3][3]);
  }
  #pragma unroll
  for(int rr=0; rr<4; rr++){
    int r = row0 + ty*4 + rr;
    if(r < NN){
      float dv = dl[ty*4+rr];
      unsigned lo = f2us(acc[rr][0]*dv) | ((unsigned)f2us(acc[rr][1]*dv) << 16);
      unsigned hi = f2us(acc[rr][2]*dv) | ((unsigned)f2us(acc[rr][3]*dv) << 16);
      uint2 o; o.x = lo; o.y = hi;
      *(uint2*)((unsigned short*)s + (size_t)r*64 + tx*4) = o;
    }
  }
}

// ---------------- CSR aggregate + finalize, 8-deep MLP unroll ----------------
__global__ void k_aggregate(const int* __restrict__ rowptr, const int* __restrict__ srcS,
                            const bf16* __restrict__ s, const float* __restrict__ dinv,
                            const float* __restrict__ b, bf16* __restrict__ h){
  int t = blockIdx.x*256 + threadIdx.x;   // grid NN*64/256
  int i = t>>6, c = t&63;
  int beg = rowptr[i], end = rowptr[i+1];
  float a0 = b2f(s[(size_t)i*64 + c]);    // self-loop
  float a1=0,a2=0,a3=0,a4=0,a5=0,a6=0,a7=0;
  int p = beg;
  for(; p+8 <= end; p += 8){
    int s0=srcS[p],   s1=srcS[p+1], s2=srcS[p+2], s3=srcS[p+3];
    int s4=srcS[p+4], s5=srcS[p+5], s6=srcS[p+6], s7=srcS[p+7];
    a0 += b2f(s[(size_t)s0*64 + c]);
    a1 += b2f(s[(size_t)s1*64 + c]);
    a2 += b2f(s[(size_t)s2*64 + c]);
    a3 += b2f(s[(size_t)s3*64 + c]);
    a4 += b2f(s[(size_t)s4*64 + c]);
    a5 += b2f(s[(size_t)s5*64 + c]);
    a6 += b2f(s[(size_t)s6*64 + c]);
    a7 += b2f(s[(size_t)s7*64 + c]);
  }
  for(; p < end; p++) a0 += b2f(s[(size_t)srcS[p]*64 + c]);
  float v = fmaxf(dinv[i]*(((a0+a1)+(a2+a3))+((a4+a5)+(a6+a7))) + b[c], 0.0f);
  int lane = threadIdx.x & 63;
  int my = (int)f2us(v);
  unsigned short g[8];
  #pragma unroll
  for(int j=0;j<8;j++) g[j] = (unsigned short)__shfl(my, lane*8 + j, 64);
  if(lane < 8){
    us8_t o;
    #pragma unroll
    for(int j=0;j<8;j++) o[j] = g[j];
    *(us8_t*)((unsigned short*)h + (size_t)i*64 + lane*8) = o;
  }
}

// ---------------- fc1: [NN x 64] @ [64 x 128] + b, relu -> f (bf16) ----------------
// 64-row tile/block, thread tile 4 rows x 8 cols
__global__ void __launch_bounds__(256) k_fc1(const bf16* __restrict__ h,
                                             const float* __restrict__ Wc,
                                             bf16* __restrict__ f){
  __shared__ float W1s[64*128];   // 32 KB
  __shared__ float hs[64][68];    // 17.4 KB
  __shared__ float bs[128];
  int tid = threadIdx.x;
  for(int j=tid; j<8192; j+=256) W1s[j] = Wc[FW1F+j];
  if(tid < 128) bs[tid] = Wc[FB1F+tid];
  int row0 = blockIdx.x*64;
  for(int ch = tid; ch < 512; ch += 256){
    int r = ch>>3, c8 = (ch&7)*8, gr = row0 + r;
    float fv[8];
    if(gr < NN){
      us8_t v = *(const us8_t*)((const unsigned short*)h + (size_t)gr*64 + c8);
      #pragma unroll
      for(int j=0;j<8;j++) fv[j] = us2f(v[j]);
    } else {
      #pragma unroll
      for(int j=0;j<8;j++) fv[j] = 0.0f;
    }
    *(float4*)&hs[r][c8]   = make_float4(fv[0],fv[1],fv[2],fv[3]);
    *(float4*)&hs[r][c8+4] = make_float4(fv[4],fv[5],fv[6],fv[7]);
  }
  __syncthreads();
  int ty = tid>>4, tx = tid&15;   // rows ty*4..+3, cols tx*8..+7
  float acc[4][8] = {{0}};
  #pragma unroll 4
  for(int k=0;k<64;k++){
    float4 b0 = *(const float4*)&W1s[k*128 + tx*8];
    float4 b1 = *(const float4*)&W1s[k*128 + tx*8 + 4];
    float a0 = hs[ty*4+0][k], a1 = hs[ty*4+1][k];
    float a2 = hs[ty*4+2][k], a3 = hs[ty*4+3][k];
    acc[0][0]=fmaf(a0,b0.x,acc[0][0]); acc[0][1]=fmaf(a0,b0.y,acc[0][1]);
    acc[0][2]=fmaf(a0,b0.z,acc[0][2]); acc[0][3]=fmaf(a0,b0.w,acc[0][3]);
    acc[0][4]=fmaf(a0,b1.x,acc[0][4]); acc[0][5]=fmaf(a0,b1.y,acc[0][5]);
    acc[0][6]=fmaf(a0,b1.z,acc[0][6]); acc[0][7]=fmaf(a0,b1.w,acc[0][7]);
    acc[1][0]=fmaf(a1,b0.x,acc[1][0]); acc[1][1]=fmaf(a1,b0.y,acc[1][1]);
    acc[1][2]=fmaf(a1,b0.z,acc[1][2]); acc[1][3]=fmaf(a1,b0.w,acc[1][3]);
    acc[1][4]=fmaf(a1,b1.x,acc[1][4]); acc[1][5]=fmaf(a1,b1.y,acc[1][5]);
    acc[1][6]=fmaf(a1,b1.z,acc[1][6]); acc[1][7]=fmaf(a1,b1.w,acc[1][7]);
    acc[2][0]=fmaf(a2,b0.x,acc[2][0]); acc[2][1]=fmaf(a2,b0.y,acc[2][1]);
    acc[2][2]=fmaf(a2,b0.z,acc[2][2]); acc[2][3]=fmaf(a2,b0.w,acc[2][3]);
    acc[2][4]=fmaf(a2,b1.x,acc[2][4]); acc[2][5]=fmaf(a2,b1.y,acc[2][5]);
    acc[2][6]=fmaf(a2,b1.z,acc[2][6]); acc[2][7]=fmaf(a2,b1.w,acc[2][7]);
    acc[3][0]=fmaf(a3,b0.x,acc[3][0]); acc[3][1]=fmaf(a3,b0.y,acc[3][1]);
    acc[3][2]=fmaf(a3,b0.z,acc[3][2]); acc[3][3]=fmaf(a3,b0.w,acc[3][3]);
    acc[3][4]=fmaf(a3,b1.x,acc[3][4]); acc[3][5]=fmaf(a3,b1.y,acc[3][5]);
    acc[3][6]=fmaf(a3,b1.z,acc[3][6]); acc[3][7]=fmaf(a3,b1.w,acc[3][7]);
  }
  #pragma unroll
  for(int r=0;r<4;r++){
    int gr = row0 + ty*4 + r;
    if(gr < NN){
      us8_t o;
      #pragma unroll
      for(int j=0;j<8;j++) o[j] = f2us(fmaxf(acc[r][j] + bs[tx*8+j], 0.0f));
      *(us8_t*)((unsigned short*)f + (size_t)gr*128 + tx*8) = o;
    }
  }
}

// ---------------- fc2: [NN x 128] @ [128 x 32] + b -> out ----------------
// 64-row tile/block, thread tile 2 rows x 4 cols
__global__ void __launch_bounds__(256) k_fc2(const bf16* __restrict__ f,
                                             const float* __restrict__ Wc,
                                             const int* __restrict__ flag,
                                             void* __restrict__ outv){
  __shared__ float W2s[128*32];   // 16 KB
  __shared__ float fs[64][132];   // 33.8 KB
  __shared__ float bs[32];
  int tid = threadIdx.x;
  for(int j=tid; j<4096; j+=256) W2s[j] = Wc[FW2F+j];
  if(tid < 32) bs[tid] = Wc[FB2F+tid];
  int row0 = blockIdx.x*64;
  for(int ch = tid; ch < 1024; ch += 256){
    int r = ch>>4, c8 = (ch&15)*8, gr = row0 + r;
    float fv[8];
    if(gr < NN){
      us8_t v = *(const us8_t*)((const unsigned short*)f + (size_t)gr*128 + c8);
      #pragma unroll
      for(int j=0;j<8;j++) fv[j] = us2f(v[j]);
    } else {
      #pragma unroll
      for(int j=0;j<8;j++) fv[j] = 0.0f;
    }
    *(float4*)&fs[r][c8]   = make_float4(fv[0],fv[1],fv[2],fv[3]);
    *(float4*)&fs[r][c8+4] = make_float4(fv[4],fv[5],fv[6],fv[7]);
  }
  __syncthreads();
  int ty = tid>>3, tx = tid&7;    // rows ty*2..+1, cols tx*4..+3
  float acc[2][4] = {{0}};
  #pragma unroll 8
  for(int k=0;k<128;k++){
    float4 b4 = *(const float4*)&W2s[k*32 + tx*4];
    float a0 = fs[ty*2+0][k], a1 = fs[ty*2+1][k];
    acc[0][0]=fmaf(a0,b4.x,acc[0][0]); acc[0][1]=fmaf(a0,b4.y,acc[0][1]);
    acc[0][2]=fmaf(a0,b4.z,acc[0][2]); acc[0][3]=fmaf(a0,b4.w,acc[0][3]);
    acc[1][0]=fmaf(a1,b4.x,acc[1][0]); acc[1][1]=fmaf(a1,b4.y,acc[1][1]);
    acc[1][2]=fmaf(a1,b4.z,acc[1][2]); acc[1][3]=fmaf(a1,b4.w,acc[1][3]);
  }
  int fl = *flag;
  #pragma unroll
  for(int r=0;r<2;r++){
    int gr = row0 + ty*2 + r;
    if(gr < NN){
      float o0 = acc[r][0]+bs[tx*4+0], o1 = acc[r][1]+bs[tx*4+1];
      float o2 = acc[r][2]+bs[tx*4+2], o3 = acc[r][3]+bs[tx*4+3];
      if(fl){
        *(float4*)((float*)outv + (size_t)gr*32 + tx*4) = make_float4(o0,o1,o2,o3);
      } else {
        unsigned lo = f2us(o0) | ((unsigned)f2us(o1)<<16);
        unsigned hi = f2us(o2) | ((unsigned)f2us(o3)<<16);
        uint2 o; o.x = lo; o.y = hi;
        *(uint2*)((unsigned short*)outv + (size_t)gr*32 + tx*4) = o;
      }
    }
  }
}

extern "C" void kernel_launch(void* const* d_in, const int* in_sizes, int n_in,
                              void* d_out, int out_size, void* d_ws, size_t ws_size,
                              hipStream_t stream){
  const void* x   = d_in[0];
  const int*  ei  = (const int*)d_in[1];
  const int* srcI = ei;        // edge_index[0]
  const int* dstI = ei + NE;   // edge_index[1]

  // workspace layout (bytes); total ~59.7 MB (round-1 precedent: 128.5 MB ran)
  char* base = (char*)d_ws;
  int*    flag   = (int*)   (base + 0);         // 256
  float*  Wc     = (float*) (base + 256);       // 83840
  int*    degc   = (int*)   (base + 84480);     // 400000 (reused as xd after CSR)
  int*    tmp    = (int*)   (base + 484608);    // 400000 (tail of xd)
  int*    bsum   = (int*)   (base + 884736);    // 512
  int*    boff   = (int*)   (base + 885248);    // 512
  int*    rowptr = (int*)   (base + 885760);    // 400004
  int*    cursor = (int*)   (base + 1286144);   // 400000 (reused as y after place)
  float*  dinv   = (float*) (base + 2086400);   // 400000
  int*    srcS   = (int*)   (base + 2486400);   // 6400000
  bf16*   s      = (bf16*)  (base + 8886400);   // 12800000
  bf16*   h      = (bf16*)  (base + 21686400);  // 12800000
  bf16*   f      = (bf16*)  (base + 34486400);  // 25600000 -> ends 60086400
  float2* xd     = (float2*)(base + 84480);     // 800000 (aliases degc+tmp, dead)
  float2* y      = (float2*)(base + 1286144);   // 800000 (aliases cursor, dead)

  k_sniff<<<1, 1024, 0, stream>>>((const unsigned short*)x, flag);
  k_convert_w<<<1, 256, 0, stream>>>(d_in[2], d_in[3], d_in[4], d_in[5], d_in[6],
                                     d_in[7], d_in[8], d_in[9], d_in[10], d_in[11],
                                     flag, Wc);

  // CSR build
  k_zero <<<(NN+255)/256, 256, 0, stream>>>(degc, NN);
  k_count<<<(NE+255)/256, 256, 0, stream>>>(dstI, degc);
  k_scan1<<<NBLK, 1024, 0, stream>>>(degc, tmp, bsum);
  k_scan2<<<1, 128, 0, stream>>>(bsum, boff);
  k_scan3<<<(NN+255)/256, 256, 0, stream>>>(tmp, boff, degc, rowptr, cursor, dinv);
  k_place<<<(NE+255)/256, 256, 0, stream>>>(srcI, dstI, cursor, srcS);

  // layer 1 (2 -> 64): propagate x first (8B gathers), then transform
  k_xd        <<<(NN+255)/256, 256, 0, stream>>>(x, flag, dinv, xd);
  k_prop_x    <<<(NN+255)/256, 256, 0, stream>>>(rowptr, srcS, xd, y);
  k_transform1b<<<NN*8/256, 256, 0, stream>>>(y, Wc, dinv, h);

  // layer 2 (64 -> 64)
  k_transform64<<<(NN+63)/64, 256, 0, stream>>>(h, Wc+W2F, dinv, s);
  k_aggregate  <<<NN*64/256, 256, 0, stream>>>(rowptr, srcS, s, dinv, Wc+B2F, h);

  // layer 3 (64 -> 64)
  k_transform64<<<(NN+63)/64, 256, 0, stream>>>(h, Wc+W3F, dinv, s);
  k_aggregate  <<<NN*64/256, 256, 0, stream>>>(rowptr, srcS, s, dinv, Wc+B3F, h);

  // fc1 + fc2 (register-tiled GEMMs)
  k_fc1<<<(NN+63)/64, 256, 0, stream>>>(h, Wc, f);
  k_fc2<<<(NN+63)/64, 256, 0, stream>>>(f, Wc, flag, d_out);
}